// Round 2
// baseline (660.373 us; speedup 1.0000x reference)
//
#include <hip/hip_runtime.h>
#include <cstdint>
#include <cstddef>

#define B_   512
#define V_   6890
#define VP   6912      // padded vertex count (27*256)
#define VP3  20736     // VP*3, pdt row length (324*64)
#define R3   20670     // V_*3
#define NJ   24
#define KF   224       // padded feature length: 207 pose + 10 betas + 1 + 6 pad
#define NP   46

// ---- constants ----
__constant__ float c_axes[47][3] = {
  { 0.f, 0.f, 1.f}, { 1.f, 0.f, 0.f}, { 0.f, 1.f, 0.f},
  { 0.f, 0.f, 1.f}, { 1.f, 0.f, 0.f}, { 0.f, 1.f, 0.f},
  { 0.f, 0.f,-1.f},
  {-0.10501402f,-0.17402183f, 0.97912636f},
  { 0.78718019f, 0.60474702f,-0.12094817f},
  { 0.58095459f, 0.00000217f,-0.81393598f},
  { 0.f, 0.f, 1.f}, {-1.f, 0.f, 0.f}, { 0.f,-1.f, 0.f},
  { 0.f, 0.f,-1.f},
  {-0.10501402f,-0.17402183f, 0.97912636f},
  {-0.78718019f,-0.60474702f,-0.12094817f},
  {-0.58095459f, 0.00000217f,-0.81393598f},
  { 1.f, 0.f, 0.f}, { 0.f, 0.f, 1.f}, { 0.f, 1.f, 0.f},
  { 1.f, 0.f, 0.f}, { 0.f, 0.f, 1.f}, { 0.f, 1.f, 0.f},
  { 1.f, 0.f, 0.f}, { 0.f, 0.f, 1.f}, { 0.f, 1.f, 0.f},
  { 0.f, 1.f, 0.f}, { 0.f, 0.f,-1.f}, {-1.f, 0.f, 0.f},
  { 1.f, 0.f, 0.f}, { 0.f, 1.f, 0.f}, { 0.f, 0.f, 1.f},
  { 0.0494f, 0.0366f, 0.99810825f},
  {-0.01716099f, 0.99266564f,-0.11966796f},
  { 1.f, 0.f, 0.f}, { 0.f, 0.f,-1.f},
  { 0.f, 1.f, 0.f}, { 0.f, 0.f, 1.f}, { 1.f, 0.f, 0.f},
  { 1.f, 0.f, 0.f}, { 0.f, 1.f, 0.f}, { 0.f, 0.f, 1.f},
  {-0.0494f,-0.0366f, 0.99810825f},
  { 0.01716099f,-0.99266564f,-0.11966796f},
  {-1.f, 0.f, 0.f}, { 0.f, 0.f,-1.f},
  { 0.f, 0.f, 0.f}
};
__constant__ int c_ridx[24][3] = {
  {0,1,2},{3,4,5},{6,46,46},{7,46,46},{8,46,46},{9,46,46},
  {10,11,12},{13,46,46},{14,46,46},{15,46,46},{16,46,46},
  {17,18,19},{20,21,22},{23,24,25},{26,27,28},{29,30,31},
  {32,46,46},{33,46,46},{34,35,46},{36,37,38},{39,40,41},
  {42,46,46},{43,46,46},{44,45,46}
};
__constant__ int c_par[24] = {-1,0,1,2,3,4,0,6,7,8,9,0,11,12,12,14,15,16,17,12,19,20,21,22};

__device__ __forceinline__ void mm3(const float* A, const float* Bm, float* C) {
#pragma unroll
  for (int i = 0; i < 3; ++i)
#pragma unroll
    for (int j = 0; j < 3; ++j)
      C[i*3+j] = A[i*3+0]*Bm[0+j] + A[i*3+1]*Bm[3+j] + A[i*3+2]*Bm[6+j];
}
__device__ __forceinline__ void mm3_bt(const float* A, const float* Bm, float* C) {
#pragma unroll
  for (int i = 0; i < 3; ++i)
#pragma unroll
    for (int j = 0; j < 3; ++j)
      C[i*3+j] = A[i*3+0]*Bm[j*3+0] + A[i*3+1]*Bm[j*3+1] + A[i*3+2]*Bm[j*3+2];
}

// ---- K0: tiled transpose -> pdt[k][r], r = v*3+c in [0,VP3), k in [0,KF) ----
// src(r,k) = posed[r*207+k] | sd[r*10+(k-207)] | vt[r] (k==217) | 0
__global__ __launch_bounds__(256) void k0_pdt(const float* __restrict__ posed,
                                              const float* __restrict__ sd,
                                              const float* __restrict__ vt,
                                              float* __restrict__ pdt) {
  __shared__ float tile[64][65];
  const int r0 = (blockIdx.x % 324) * 64;
  const int k0 = (blockIdx.x / 324) * 64;
  const int tx = threadIdx.x & 63;
  const int ty = threadIdx.x >> 6;
#pragma unroll
  for (int i = 0; i < 16; ++i) {
    int r = r0 + ty + i*4;
    int k = k0 + tx;
    float val = 0.f;
    if (r < R3) {
      if (k < 207)       val = posed[r*207 + k];
      else if (k < 217)  val = sd[r*10 + (k - 207)];
      else if (k == 217) val = vt[r];
    }
    tile[ty + i*4][tx] = val;
  }
  __syncthreads();
#pragma unroll
  for (int i = 0; i < 16; ++i) {
    int k = k0 + ty + i*4;
    if (k < KF) pdt[(size_t)k*VP3 + r0 + tx] = tile[tx][ty + i*4];
  }
}

// ---- K0b: transpose skin weights -> swt[j][v], zero-padded to VP ----
__global__ void k0b_swt(const float* __restrict__ sw, float* __restrict__ swt) {
  int i = blockIdx.x * 256 + threadIdx.x;   // 24*VP exact
  int v = i % VP, j = i / VP;
  swt[i] = (v < V_) ? sw[v*24 + j] : 0.f;
}

// ---- K1: per-joint regression: jts[j][c][0]=Jreg@vt ; jts[j][c][1+kb]=Jreg@sd ----
__global__ __launch_bounds__(256) void k1_jts(const float* __restrict__ jreg,
                                              const float* __restrict__ vt,
                                              const float* __restrict__ sd,
                                              float* __restrict__ jts) {
  const int j = blockIdx.x;
  float acc[3][11];
#pragma unroll
  for (int c = 0; c < 3; ++c)
#pragma unroll
    for (int i = 0; i < 11; ++i) acc[c][i] = 0.f;
  for (int v = threadIdx.x; v < V_; v += 256) {
    float wgt = jreg[j*V_ + v];
#pragma unroll
    for (int c = 0; c < 3; ++c) {
      acc[c][0] += wgt * vt[v*3 + c];
      const float* s = sd + (v*3 + c)*10;
#pragma unroll
      for (int k = 0; k < 10; ++k) acc[c][1+k] += wgt * s[k];
    }
  }
#pragma unroll
  for (int c = 0; c < 3; ++c)
#pragma unroll
    for (int i = 0; i < 11; ++i)
#pragma unroll
      for (int o = 32; o > 0; o >>= 1) acc[c][i] += __shfl_xor(acc[c][i], o, 64);
  __shared__ float red[4][33];
  int wid = threadIdx.x >> 6, ln = threadIdx.x & 63;
  if (ln == 0) {
#pragma unroll
    for (int c = 0; c < 3; ++c)
#pragma unroll
      for (int i = 0; i < 11; ++i) red[wid][c*11+i] = acc[c][i];
  }
  __syncthreads();
  if (threadIdx.x < 33)
    jts[j*33 + threadIdx.x] = red[0][threadIdx.x] + red[1][threadIdx.x] +
                              red[2][threadIdx.x] + red[3][threadIdx.x];
}

// ---- K2: per-batch pose math -> F[b][224], M[b][24][12] ----
__global__ void k2_pose(const float* __restrict__ poses, const float* __restrict__ betas,
                        const float* __restrict__ trans, const float* __restrict__ apose,
                        const float* __restrict__ pjr, const float* __restrict__ jts,
                        float* __restrict__ Fw, float* __restrict__ Mw) {
  const int b = blockIdx.x;
  const int t = threadIdx.x;
  __shared__ float Rd[47][9];
  __shared__ float Rj[24][9];
  __shared__ float Rl[24][9];
  __shared__ float jl[24][3];
  __shared__ float G[24][12];

  if (t < 47) {
    float q  = (t < NP) ? poses[b*NP + t] : 0.f;
    float ax = c_axes[t][0], ay = c_axes[t][1], az = c_axes[t][2];
    float s = sinf(q), cq = cosf(q);
    float u = 1.f - cq;
    Rd[t][0] = u*ax*ax + cq;   Rd[t][1] = u*ax*ay - s*az; Rd[t][2] = u*ax*az + s*ay;
    Rd[t][3] = u*ax*ay + s*az; Rd[t][4] = u*ay*ay + cq;   Rd[t][5] = u*ay*az - s*ax;
    Rd[t][6] = u*ax*az - s*ay; Rd[t][7] = u*ay*az + s*ax; Rd[t][8] = u*az*az + cq;
  }
  if (t < NJ) {
    const float* jr = jts + t*33;
#pragma unroll
    for (int c = 0; c < 3; ++c) {
      float a = jr[c*11];
#pragma unroll
      for (int k = 0; k < 10; ++k) a += jr[c*11 + 1 + k] * betas[b*10 + k];
      jl[t][c] = a;
    }
  }
  __syncthreads();
  if (t < NJ) {
    float C1[9], C2[9];
    const int r0 = c_ridx[t][0], r1 = c_ridx[t][1], r2 = c_ridx[t][2];
    mm3(&Rd[r0][0], &Rd[r1][0], C1);
    mm3(C1, &Rd[r2][0], C2);
#pragma unroll
    for (int e = 0; e < 9; ++e) Rj[t][e] = C2[e];
    float P[9], Ap[9];
#pragma unroll
    for (int e = 0; e < 9; ++e) { P[e] = pjr[t*9 + e]; Ap[e] = apose[t*9 + e]; }
    mm3(P, C2, C1);
    mm3_bt(C1, P, C2);
    mm3(Ap, C2, C1);
#pragma unroll
    for (int e = 0; e < 9; ++e) Rl[t][e] = C1[e];
  }
  __syncthreads();
  if (t == 0) {
#pragma unroll
    for (int e = 0; e < 9; ++e) G[0][e] = Rl[0][e];
    G[0][9] = jl[0][0]; G[0][10] = jl[0][1]; G[0][11] = jl[0][2];
    for (int j = 1; j < NJ; ++j) {
      int p = c_par[j];
      float R[9];
      mm3(&G[p][0], &Rl[j][0], R);
#pragma unroll
      for (int e = 0; e < 9; ++e) G[j][e] = R[e];
      float d0 = jl[j][0]-jl[p][0], d1 = jl[j][1]-jl[p][1], d2 = jl[j][2]-jl[p][2];
      G[j][9]  = G[p][9]  + G[p][0]*d0 + G[p][1]*d1 + G[p][2]*d2;
      G[j][10] = G[p][10] + G[p][3]*d0 + G[p][4]*d1 + G[p][5]*d2;
      G[j][11] = G[p][11] + G[p][6]*d0 + G[p][7]*d1 + G[p][8]*d2;
    }
  }
  __syncthreads();
  if (t < NJ) {
    float tx = trans[b*3+0], ty = trans[b*3+1], tz = trans[b*3+2];
    float a0 = G[t][9]  - (G[t][0]*jl[t][0] + G[t][1]*jl[t][1] + G[t][2]*jl[t][2]) + tx;
    float a1 = G[t][10] - (G[t][3]*jl[t][0] + G[t][4]*jl[t][1] + G[t][5]*jl[t][2]) + ty;
    float a2 = G[t][11] - (G[t][6]*jl[t][0] + G[t][7]*jl[t][1] + G[t][8]*jl[t][2]) + tz;
    float* m = Mw + b*288 + t*12;
#pragma unroll
    for (int e = 0; e < 9; ++e) m[e] = G[t][e];
    m[9] = a0; m[10] = a1; m[11] = a2;
  }
  for (int k = t; k < KF; k += 64) {
    float val;
    if (k < 207) {
      int jj = k / 9 + 1;
      int e  = k % 9;
      val = Rj[jj][e] - ((e == 0 || e == 4 || e == 8) ? 1.f : 0.f);
    } else if (k < 217) val = betas[b*10 + (k - 207)];
    else if (k == 217)  val = 1.f;
    else                val = 0.f;
    Fw[b*KF + k] = val;
  }
}

// ---- K3: fused GEMM + skinning. 128 thr = 2 waves; block = 256v x 8b; thread 2v x 8b ----
__global__ __launch_bounds__(128, 4) void k3_verts(
    const float* __restrict__ pdt,   // [KF][VP3]
    const float* __restrict__ Fw,    // [B][KF]
    const float* __restrict__ Mw,    // [B][24][12]
    const float* __restrict__ swt,   // [24][VP]
    float* __restrict__ out)         // [B][V][3]
{
  __shared__ float smem[8*288];      // phase 1: Flt[224][8]; phase 2: Ml[8][12*24]
  const int bt = blockIdx.x & 63;    // b-tile fast -> 64 consecutive blocks share pdt v-range
  const int vt = blockIdx.x >> 6;
  const int b0 = bt * 8;
  const int t  = threadIdx.x;

  // stage F transposed: smem[k*8 + bb] = Fw[(b0+bb)*KF + k]
  for (int idx = t; idx < KF*8; idx += 128) {
    int bb = idx & 7, k = idx >> 3;
    smem[idx] = Fw[(b0 + bb)*KF + k];
  }
  __syncthreads();

  const int lane = t & 63;
  const int w    = t >> 6;
  const int v0   = vt*256 + w*128 + lane*2;       // 2 consecutive vertices, all distinct per wave
  const float* pB = pdt + (size_t)v0*3;

  float acc[8][6];                                // [bb][vi*3+c]
#pragma unroll
  for (int bb = 0; bb < 8; ++bb)
#pragma unroll
    for (int e = 0; e < 6; ++e) acc[bb][e] = 0.f;

#pragma unroll 2
  for (int k = 0; k < KF; ++k) {
    float2 p0 = *(const float2*)(pB);
    float2 p1 = *(const float2*)(pB + 2);
    float2 p2 = *(const float2*)(pB + 4);
    float4 fa = *(const float4*)(smem + k*8);
    float4 fb = *(const float4*)(smem + k*8 + 4);
    float p[6] = {p0.x, p0.y, p1.x, p1.y, p2.x, p2.y};
#pragma unroll
    for (int bb = 0; bb < 4; ++bb) {
      float f = (&fa.x)[bb];
#pragma unroll
      for (int e = 0; e < 6; ++e) acc[bb][e] += p[e]*f;
    }
#pragma unroll
    for (int bb = 0; bb < 4; ++bb) {
      float f = (&fb.x)[bb];
#pragma unroll
      for (int e = 0; e < 6; ++e) acc[4+bb][e] += p[e]*f;
    }
    pB += VP3;
  }
  __syncthreads();

  // stage M (reuse smem): 8 batches x [24][12]
  for (int idx = t; idx < 8*288; idx += 128) smem[idx] = Mw[b0*288 + idx];
  __syncthreads();

  float vo[8][6];
#pragma unroll
  for (int bb = 0; bb < 8; ++bb)
#pragma unroll
    for (int e = 0; e < 6; ++e) vo[bb][e] = 0.f;

#pragma unroll 1
  for (int j = 0; j < NJ; ++j) {
    float2 s2 = *(const float2*)(swt + j*VP + v0);
#pragma unroll
    for (int bb = 0; bb < 8; ++bb) {
      const float* m = smem + bb*288 + j*12;
      float4 m0 = *(const float4*)(m);
      float4 m1 = *(const float4*)(m + 4);
      float4 m2 = *(const float4*)(m + 8);
      {
        float x = acc[bb][0], y = acc[bb][1], z = acc[bb][2];
        vo[bb][0] += s2.x*(m0.x*x + m0.y*y + m0.z*z + m2.y);
        vo[bb][1] += s2.x*(m0.w*x + m1.x*y + m1.y*z + m2.z);
        vo[bb][2] += s2.x*(m1.z*x + m1.w*y + m2.x*z + m2.w);
      }
      {
        float x = acc[bb][3], y = acc[bb][4], z = acc[bb][5];
        vo[bb][3] += s2.y*(m0.x*x + m0.y*y + m0.z*z + m2.y);
        vo[bb][4] += s2.y*(m0.w*x + m1.x*y + m1.y*z + m2.z);
        vo[bb][5] += s2.y*(m1.z*x + m1.w*y + m2.x*z + m2.w);
      }
    }
  }

  if (v0 < V_) {                                   // V_ even, v0 even -> both vertices valid
#pragma unroll
    for (int bb = 0; bb < 8; ++bb) {
      float* o = out + ((size_t)(b0 + bb)*V_ + v0)*3;
      *(float2*)(o)     = make_float2(vo[bb][0], vo[bb][1]);
      *(float2*)(o + 2) = make_float2(vo[bb][2], vo[bb][3]);
      *(float2*)(o + 4) = make_float2(vo[bb][4], vo[bb][5]);
    }
  }
}

extern "C" void kernel_launch(void* const* d_in, const int* in_sizes, int n_in,
                              void* d_out, int out_size, void* d_ws, size_t ws_size,
                              hipStream_t stream) {
  (void)in_sizes; (void)n_in; (void)out_size; (void)ws_size;
  const float* betas      = (const float*)d_in[0];
  const float* poses      = (const float*)d_in[1];
  const float* trans      = (const float*)d_in[2];
  const float* v_template = (const float*)d_in[3];
  const float* shapedirs  = (const float*)d_in[4];
  const float* posedirs   = (const float*)d_in[5];
  const float* jreg       = (const float*)d_in[6];
  const float* skinw      = (const float*)d_in[7];
  const float* apose      = (const float*)d_in[8];
  const float* pjr        = (const float*)d_in[9];
  float* out = (float*)d_out;
  float* ws  = (float*)d_ws;

  float* pdt = ws;                       // KF*VP3        = 4,644,864 floats
  float* Fw  = ws + 4644864;             // B*KF          =   114,688
  float* Mw  = ws + 4759552;             // B*24*12       =   147,456
  float* jts = ws + 4907008;             // 24*33         =       792
  float* swt = ws + 4907800;             // 24*VP         =   165,888   (total 20.3 MB)

  hipLaunchKernelGGL(k0_pdt, dim3(324*4), dim3(256), 0, stream,
                     posedirs, shapedirs, v_template, pdt);
  hipLaunchKernelGGL(k0b_swt, dim3(24*VP/256), dim3(256), 0, stream, skinw, swt);
  hipLaunchKernelGGL(k1_jts, dim3(24), dim3(256), 0, stream,
                     jreg, v_template, shapedirs, jts);
  hipLaunchKernelGGL(k2_pose, dim3(B_), dim3(64), 0, stream,
                     poses, betas, trans, apose, pjr, jts, Fw, Mw);
  hipLaunchKernelGGL(k3_verts, dim3(64 * (VP/256)), dim3(128), 0, stream,
                     pdt, Fw, Mw, swt, out);
}

// Round 3
// 192.245 us; speedup vs baseline: 3.4351x; 3.4351x over previous
//
#include <hip/hip_runtime.h>
#include <cstdint>
#include <cstddef>

#define B_   512
#define V_   6890
#define VP   6912      // padded vertex count (432*16)
#define NJ   24
#define KF   224       // padded K: 207 pose + 10 betas + 1 + 6 pad (7 tiles of 32)
#define NP   46
#define NVT  432       // 16-v tiles
#define NBT  32        // 16-b tiles
#define NKT  7         // 32-k tiles

typedef float f32x4 __attribute__((ext_vector_type(4)));
typedef short s16x8 __attribute__((ext_vector_type(8)));

__device__ __forceinline__ unsigned short f2bf(float f) {
  unsigned int u = __float_as_uint(f);
  u = (u + 0x7FFFu + ((u >> 16) & 1u)) >> 16;
  return (unsigned short)u;
}

// ---- constants ----
__constant__ float c_axes[47][3] = {
  { 0.f, 0.f, 1.f}, { 1.f, 0.f, 0.f}, { 0.f, 1.f, 0.f},
  { 0.f, 0.f, 1.f}, { 1.f, 0.f, 0.f}, { 0.f, 1.f, 0.f},
  { 0.f, 0.f,-1.f},
  {-0.10501402f,-0.17402183f, 0.97912636f},
  { 0.78718019f, 0.60474702f,-0.12094817f},
  { 0.58095459f, 0.00000217f,-0.81393598f},
  { 0.f, 0.f, 1.f}, {-1.f, 0.f, 0.f}, { 0.f,-1.f, 0.f},
  { 0.f, 0.f,-1.f},
  {-0.10501402f,-0.17402183f, 0.97912636f},
  {-0.78718019f,-0.60474702f,-0.12094817f},
  {-0.58095459f, 0.00000217f,-0.81393598f},
  { 1.f, 0.f, 0.f}, { 0.f, 0.f, 1.f}, { 0.f, 1.f, 0.f},
  { 1.f, 0.f, 0.f}, { 0.f, 0.f, 1.f}, { 0.f, 1.f, 0.f},
  { 1.f, 0.f, 0.f}, { 0.f, 0.f, 1.f}, { 0.f, 1.f, 0.f},
  { 0.f, 1.f, 0.f}, { 0.f, 0.f,-1.f}, {-1.f, 0.f, 0.f},
  { 1.f, 0.f, 0.f}, { 0.f, 1.f, 0.f}, { 0.f, 0.f, 1.f},
  { 0.0494f, 0.0366f, 0.99810825f},
  {-0.01716099f, 0.99266564f,-0.11966796f},
  { 1.f, 0.f, 0.f}, { 0.f, 0.f,-1.f},
  { 0.f, 1.f, 0.f}, { 0.f, 0.f, 1.f}, { 1.f, 0.f, 0.f},
  { 1.f, 0.f, 0.f}, { 0.f, 1.f, 0.f}, { 0.f, 0.f, 1.f},
  {-0.0494f,-0.0366f, 0.99810825f},
  { 0.01716099f,-0.99266564f,-0.11966796f},
  {-1.f, 0.f, 0.f}, { 0.f, 0.f,-1.f},
  { 0.f, 0.f, 0.f}
};
__constant__ int c_ridx[24][3] = {
  {0,1,2},{3,4,5},{6,46,46},{7,46,46},{8,46,46},{9,46,46},
  {10,11,12},{13,46,46},{14,46,46},{15,46,46},{16,46,46},
  {17,18,19},{20,21,22},{23,24,25},{26,27,28},{29,30,31},
  {32,46,46},{33,46,46},{34,35,46},{36,37,38},{39,40,41},
  {42,46,46},{43,46,46},{44,45,46}
};
__constant__ int c_par[24] = {-1,0,1,2,3,4,0,6,7,8,9,0,11,12,12,14,15,16,17,12,19,20,21,22};

__device__ __forceinline__ void mm3(const float* A, const float* Bm, float* C) {
#pragma unroll
  for (int i = 0; i < 3; ++i)
#pragma unroll
    for (int j = 0; j < 3; ++j)
      C[i*3+j] = A[i*3+0]*Bm[0+j] + A[i*3+1]*Bm[3+j] + A[i*3+2]*Bm[6+j];
}
__device__ __forceinline__ void mm3_bt(const float* A, const float* Bm, float* C) {
#pragma unroll
  for (int i = 0; i < 3; ++i)
#pragma unroll
    for (int j = 0; j < 3; ++j)
      C[i*3+j] = A[i*3+0]*Bm[j*3+0] + A[i*3+1]*Bm[j*3+1] + A[i*3+2]*Bm[j*3+2];
}

// ---- K0: PD -> bf16 MFMA-A fragment layout pdm[c][vt][kt][lane][8] ----
// A-frag (16x16x32): row(v) = lane&15, k = (lane>>4)*8 + j
__global__ __launch_bounds__(256) void k0_pdm(const float* __restrict__ posed,
                                              const float* __restrict__ sd,
                                              const float* __restrict__ vt,
                                              unsigned short* __restrict__ pdm) {
  int t = blockIdx.x * 256 + threadIdx.x;      // exact grid: 3*432*7*64
  int lane = t & 63;
  int tile = t >> 6;                           // 0..9071, kt fastest for row reuse
  int kt = tile % NKT;
  int vtg = (tile / NKT) % NVT;
  int c  = tile / (NKT * NVT);
  int v  = vtg*16 + (lane & 15);
  int kb = kt*32 + (lane >> 4)*8;
  unsigned short vals[8];
#pragma unroll
  for (int j = 0; j < 8; ++j) {
    int k = kb + j;
    float f = 0.f;
    if (v < V_) {
      if (k < 207)       f = posed[(v*3 + c)*207 + k];
      else if (k < 217)  f = sd[(v*3 + c)*10 + (k - 207)];
      else if (k == 217) f = vt[v*3 + c];
    }
    vals[j] = f2bf(f);
  }
  *(uint4*)(pdm + (size_t)tile*512 + lane*8) = *(const uint4*)vals;
}

// ---- K0b: skin weights -> swt[j][v] f32, zero-padded ----
__global__ void k0b_swt(const float* __restrict__ sw, float* __restrict__ swt) {
  int i = blockIdx.x * 256 + threadIdx.x;   // 24*VP exact
  int v = i % VP, j = i / VP;
  swt[i] = (v < V_) ? sw[v*24 + j] : 0.f;
}

// ---- K1: jts[j][c][0]=Jreg@vt ; jts[j][c][1+kb]=Jreg@sd ----
__global__ __launch_bounds__(256) void k1_jts(const float* __restrict__ jreg,
                                              const float* __restrict__ vt,
                                              const float* __restrict__ sd,
                                              float* __restrict__ jts) {
  const int j = blockIdx.x;
  float acc[3][11];
#pragma unroll
  for (int c = 0; c < 3; ++c)
#pragma unroll
    for (int i = 0; i < 11; ++i) acc[c][i] = 0.f;
  for (int v = threadIdx.x; v < V_; v += 256) {
    float wgt = jreg[j*V_ + v];
#pragma unroll
    for (int c = 0; c < 3; ++c) {
      acc[c][0] += wgt * vt[v*3 + c];
      const float* s = sd + (v*3 + c)*10;
#pragma unroll
      for (int k = 0; k < 10; ++k) acc[c][1+k] += wgt * s[k];
    }
  }
#pragma unroll
  for (int c = 0; c < 3; ++c)
#pragma unroll
    for (int i = 0; i < 11; ++i)
#pragma unroll
      for (int o = 32; o > 0; o >>= 1) acc[c][i] += __shfl_xor(acc[c][i], o, 64);
  __shared__ float red[4][33];
  int wid = threadIdx.x >> 6, ln = threadIdx.x & 63;
  if (ln == 0) {
#pragma unroll
    for (int c = 0; c < 3; ++c)
#pragma unroll
      for (int i = 0; i < 11; ++i) red[wid][c*11+i] = acc[c][i];
  }
  __syncthreads();
  if (threadIdx.x < 33)
    jts[j*33 + threadIdx.x] = red[0][threadIdx.x] + red[1][threadIdx.x] +
                              red[2][threadIdx.x] + red[3][threadIdx.x];
}

// ---- K2: per-batch pose math -> Fw[b][224] f32, Mw[b][24][12] f32 ----
__global__ void k2_pose(const float* __restrict__ poses, const float* __restrict__ betas,
                        const float* __restrict__ trans, const float* __restrict__ apose,
                        const float* __restrict__ pjr, const float* __restrict__ jts,
                        float* __restrict__ Fw, float* __restrict__ Mw) {
  const int b = blockIdx.x;
  const int t = threadIdx.x;
  __shared__ float Rd[47][9];
  __shared__ float Rj[24][9];
  __shared__ float Rl[24][9];
  __shared__ float jl[24][3];
  __shared__ float G[24][12];

  if (t < 47) {
    float q  = (t < NP) ? poses[b*NP + t] : 0.f;
    float ax = c_axes[t][0], ay = c_axes[t][1], az = c_axes[t][2];
    float s = sinf(q), cq = cosf(q);
    float u = 1.f - cq;
    Rd[t][0] = u*ax*ax + cq;   Rd[t][1] = u*ax*ay - s*az; Rd[t][2] = u*ax*az + s*ay;
    Rd[t][3] = u*ax*ay + s*az; Rd[t][4] = u*ay*ay + cq;   Rd[t][5] = u*ay*az - s*ax;
    Rd[t][6] = u*ax*az - s*ay; Rd[t][7] = u*ay*az + s*ax; Rd[t][8] = u*az*az + cq;
  }
  if (t < NJ) {
    const float* jr = jts + t*33;
#pragma unroll
    for (int c = 0; c < 3; ++c) {
      float a = jr[c*11];
#pragma unroll
      for (int k = 0; k < 10; ++k) a += jr[c*11 + 1 + k] * betas[b*10 + k];
      jl[t][c] = a;
    }
  }
  __syncthreads();
  if (t < NJ) {
    float C1[9], C2[9];
    const int r0 = c_ridx[t][0], r1 = c_ridx[t][1], r2 = c_ridx[t][2];
    mm3(&Rd[r0][0], &Rd[r1][0], C1);
    mm3(C1, &Rd[r2][0], C2);
#pragma unroll
    for (int e = 0; e < 9; ++e) Rj[t][e] = C2[e];
    float P[9], Ap[9];
#pragma unroll
    for (int e = 0; e < 9; ++e) { P[e] = pjr[t*9 + e]; Ap[e] = apose[t*9 + e]; }
    mm3(P, C2, C1);
    mm3_bt(C1, P, C2);
    mm3(Ap, C2, C1);
#pragma unroll
    for (int e = 0; e < 9; ++e) Rl[t][e] = C1[e];
  }
  __syncthreads();
  if (t == 0) {
#pragma unroll
    for (int e = 0; e < 9; ++e) G[0][e] = Rl[0][e];
    G[0][9] = jl[0][0]; G[0][10] = jl[0][1]; G[0][11] = jl[0][2];
    for (int j = 1; j < NJ; ++j) {
      int p = c_par[j];
      float R[9];
      mm3(&G[p][0], &Rl[j][0], R);
#pragma unroll
      for (int e = 0; e < 9; ++e) G[j][e] = R[e];
      float d0 = jl[j][0]-jl[p][0], d1 = jl[j][1]-jl[p][1], d2 = jl[j][2]-jl[p][2];
      G[j][9]  = G[p][9]  + G[p][0]*d0 + G[p][1]*d1 + G[p][2]*d2;
      G[j][10] = G[p][10] + G[p][3]*d0 + G[p][4]*d1 + G[p][5]*d2;
      G[j][11] = G[p][11] + G[p][6]*d0 + G[p][7]*d1 + G[p][8]*d2;
    }
  }
  __syncthreads();
  if (t < NJ) {
    float tx = trans[b*3+0], ty = trans[b*3+1], tz = trans[b*3+2];
    float a0 = G[t][9]  - (G[t][0]*jl[t][0] + G[t][1]*jl[t][1] + G[t][2]*jl[t][2]) + tx;
    float a1 = G[t][10] - (G[t][3]*jl[t][0] + G[t][4]*jl[t][1] + G[t][5]*jl[t][2]) + ty;
    float a2 = G[t][11] - (G[t][6]*jl[t][0] + G[t][7]*jl[t][1] + G[t][8]*jl[t][2]) + tz;
    float* m = Mw + b*288 + t*12;
#pragma unroll
    for (int e = 0; e < 9; ++e) m[e] = G[t][e];
    m[9] = a0; m[10] = a1; m[11] = a2;
  }
  for (int k = t; k < KF; k += 64) {
    float val;
    if (k < 207) {
      int jj = k / 9 + 1;
      int e  = k % 9;
      val = Rj[jj][e] - ((e == 0 || e == 4 || e == 8) ? 1.f : 0.f);
    } else if (k < 217) val = betas[b*10 + (k - 207)];
    else if (k == 217)  val = 1.f;
    else                val = 0.f;
    Fw[b*KF + k] = val;
  }
}

// ---- K2b: F -> bf16 MFMA-B fragment layout fmf[bt][kt][lane][8] ----
// B-frag: col(b) = lane&15, k = (lane>>4)*8 + j
__global__ void k2b_fmf(const float* __restrict__ Fw, unsigned short* __restrict__ fmf) {
  int t = blockIdx.x * 256 + threadIdx.x;      // exact: 32*7*64
  int lane = t & 63;
  int tile = t >> 6;
  int kt = tile % NKT;
  int bt = tile / NKT;
  int b  = bt*16 + (lane & 15);
  int kb = kt*32 + (lane >> 4)*8;
  unsigned short vals[8];
#pragma unroll
  for (int j = 0; j < 8; ++j) vals[j] = f2bf(Fw[b*KF + kb + j]);
  *(uint4*)(fmf + (size_t)tile*512 + lane*8) = *(const uint4*)vals;
}

// ---- K3: MFMA GEMM (v_posed) + in-register skinning ----
// block = 4 waves; wave tile 32v x 32b (2x2 MFMA tiles x 3 components)
__global__ __launch_bounds__(256) void k3_verts(
    const unsigned short* __restrict__ pdm,  // [3][432][7][64][8] bf16
    const unsigned short* __restrict__ fmf,  // [32][7][64][8] bf16
    const float* __restrict__ Mw,            // [512][24][12]
    const float* __restrict__ swt,           // [24][VP]
    float* __restrict__ out)                 // [B][V][3]
{
  const int t    = threadIdx.x;
  const int lane = t & 63;
  const int w    = t >> 6;
  const int wv   = w >> 1, wb = w & 1;
  const int bt_blk = blockIdx.x & 7;         // fastest -> 8 blocks share A slice
  const int vt_blk = blockIdx.x >> 3;        // 0..107

  const int vtg0 = vt_blk*4 + wv*2;          // two 16-v tiles: vtg0, vtg0+1
  const int btg0 = bt_blk*4 + wb*2;          // two 16-b tiles

  f32x4 acc[2][2][3];                        // [vsel][bsel][c]
#pragma unroll
  for (int a = 0; a < 2; ++a)
#pragma unroll
    for (int bsl = 0; bsl < 2; ++bsl)
#pragma unroll
      for (int c = 0; c < 3; ++c) acc[a][bsl][c] = (f32x4){0.f,0.f,0.f,0.f};

#pragma unroll 1
  for (int kt = 0; kt < NKT; ++kt) {
    s16x8 af[2][3], bf[2];
#pragma unroll
    for (int vs = 0; vs < 2; ++vs)
#pragma unroll
      for (int c = 0; c < 3; ++c)
        af[vs][c] = *(const s16x8*)(pdm + (((size_t)(c*NVT + vtg0 + vs))*NKT + kt)*512 + lane*8);
#pragma unroll
    for (int bs = 0; bs < 2; ++bs)
      bf[bs] = *(const s16x8*)(fmf + ((size_t)(btg0 + bs)*NKT + kt)*512 + lane*8);
#pragma unroll
    for (int vs = 0; vs < 2; ++vs)
#pragma unroll
      for (int bs = 0; bs < 2; ++bs)
#pragma unroll
        for (int c = 0; c < 3; ++c)
          acc[vs][bs][c] = __builtin_amdgcn_mfma_f32_16x16x32_bf16(af[vs][c], bf[bs], acc[vs][bs][c], 0, 0, 0);
  }

  // skinning in-register: lane holds v = vtg*16 + (lane>>4)*4 + q (q=reg), b = btg*16 + (lane&15)
  const int vb0 = vtg0*16 + (lane >> 4)*4;   // vsel adds 16
  const int bi0 = btg0*16 + (lane & 15);     // bsel adds 16

  float vo[2][2][3][4];
#pragma unroll
  for (int vs = 0; vs < 2; ++vs)
#pragma unroll
    for (int bs = 0; bs < 2; ++bs)
#pragma unroll
      for (int c = 0; c < 3; ++c)
#pragma unroll
        for (int q = 0; q < 4; ++q) vo[vs][bs][c][q] = 0.f;

#pragma unroll 1
  for (int j = 0; j < NJ; ++j) {
    float4 s4[2];
#pragma unroll
    for (int vs = 0; vs < 2; ++vs)
      s4[vs] = *(const float4*)(swt + (size_t)j*VP + vb0 + vs*16);
#pragma unroll
    for (int bs = 0; bs < 2; ++bs) {
      const float4* mp = (const float4*)(Mw + (size_t)(bi0 + bs*16)*288 + j*12);
      float4 m0 = mp[0], m1 = mp[1], m2 = mp[2];
#pragma unroll
      for (int vs = 0; vs < 2; ++vs) {
#pragma unroll
        for (int q = 0; q < 4; ++q) {
          float sv = (&s4[vs].x)[q];
          float x = acc[vs][bs][0][q], y = acc[vs][bs][1][q], z = acc[vs][bs][2][q];
          float r0 = fmaf(m0.z, z, fmaf(m0.y, y, fmaf(m0.x, x, m2.y)));
          float r1 = fmaf(m1.y, z, fmaf(m1.x, y, fmaf(m0.w, x, m2.z)));
          float r2 = fmaf(m2.x, z, fmaf(m1.w, y, fmaf(m1.z, x, m2.w)));
          vo[vs][bs][0][q] = fmaf(sv, r0, vo[vs][bs][0][q]);
          vo[vs][bs][1][q] = fmaf(sv, r1, vo[vs][bs][1][q]);
          vo[vs][bs][2][q] = fmaf(sv, r2, vo[vs][bs][2][q]);
        }
      }
    }
  }

#pragma unroll
  for (int vs = 0; vs < 2; ++vs) {
#pragma unroll
    for (int q = 0; q < 4; ++q) {
      int v = vb0 + vs*16 + q;
      if (v < V_) {
#pragma unroll
        for (int bs = 0; bs < 2; ++bs) {
          int b = bi0 + bs*16;
          float* o = out + ((size_t)b*V_ + v)*3;
          o[0] = vo[vs][bs][0][q];
          o[1] = vo[vs][bs][1][q];
          o[2] = vo[vs][bs][2][q];
        }
      }
    }
  }
}

extern "C" void kernel_launch(void* const* d_in, const int* in_sizes, int n_in,
                              void* d_out, int out_size, void* d_ws, size_t ws_size,
                              hipStream_t stream) {
  (void)in_sizes; (void)n_in; (void)out_size; (void)ws_size;
  const float* betas      = (const float*)d_in[0];
  const float* poses      = (const float*)d_in[1];
  const float* trans      = (const float*)d_in[2];
  const float* v_template = (const float*)d_in[3];
  const float* shapedirs  = (const float*)d_in[4];
  const float* posedirs   = (const float*)d_in[5];
  const float* jreg       = (const float*)d_in[6];
  const float* skinw      = (const float*)d_in[7];
  const float* apose      = (const float*)d_in[8];
  const float* pjr        = (const float*)d_in[9];
  float* out = (float*)d_out;
  float* ws  = (float*)d_ws;

  unsigned short* pdm = (unsigned short*)ws;            // 3*432*7*512 u16 = 4,644,864 (2,322,432 f32)
  unsigned short* fmf = (unsigned short*)(ws + 2322432); // 32*7*512 u16 = 114,688 (57,344 f32)
  float* Fw  = ws + 2379776;                            // 512*224   = 114,688
  float* Mw  = ws + 2494464;                            // 512*288   = 147,456
  float* jts = ws + 2641920;                            // 24*33     = 792
  float* swt = ws + 2642712;                            // 24*VP     = 165,888  (end ~11.2 MB)

  hipLaunchKernelGGL(k0_pdm, dim3(3*NVT*NKT*64/256), dim3(256), 0, stream,
                     posedirs, shapedirs, v_template, pdm);
  hipLaunchKernelGGL(k0b_swt, dim3(24*VP/256), dim3(256), 0, stream, skinw, swt);
  hipLaunchKernelGGL(k1_jts, dim3(24), dim3(256), 0, stream,
                     jreg, v_template, shapedirs, jts);
  hipLaunchKernelGGL(k2_pose, dim3(B_), dim3(64), 0, stream,
                     poses, betas, trans, apose, pjr, jts, Fw, Mw);
  hipLaunchKernelGGL(k2b_fmf, dim3(NBT*NKT*64/256), dim3(256), 0, stream, Fw, fmf);
  hipLaunchKernelGGL(k3_verts, dim3(8 * 108), dim3(256), 0, stream,
                     pdm, fmf, Mw, swt, out);
}

// Round 4
// 79.990 us; speedup vs baseline: 8.2557x; 2.4034x over previous
//
#include <hip/hip_runtime.h>
#include <cstdint>
#include <cstddef>

#define B_   512
#define V_   6890
#define VP   6912      // padded vertex count (432*16)
#define NJ   24
#define KF   224       // padded K: 207 pose + 10 betas + 1 + 6 pad (7 tiles of 32)
#define NP   46
#define NVT  432       // 16-v tiles
#define NBT  32        // 16-b tiles
#define NKT  7         // 32-k tiles

typedef float f32x4 __attribute__((ext_vector_type(4)));
typedef short s16x8 __attribute__((ext_vector_type(8)));

__device__ __forceinline__ unsigned short f2bf(float f) {
  unsigned int u = __float_as_uint(f);
  u = (u + 0x7FFFu + ((u >> 16) & 1u)) >> 16;
  return (unsigned short)u;
}
__device__ __forceinline__ float bf2f(unsigned short h) {
  return __uint_as_float(((unsigned int)h) << 16);
}

// ---- constants ----
__constant__ float c_axes[47][3] = {
  { 0.f, 0.f, 1.f}, { 1.f, 0.f, 0.f}, { 0.f, 1.f, 0.f},
  { 0.f, 0.f, 1.f}, { 1.f, 0.f, 0.f}, { 0.f, 1.f, 0.f},
  { 0.f, 0.f,-1.f},
  {-0.10501402f,-0.17402183f, 0.97912636f},
  { 0.78718019f, 0.60474702f,-0.12094817f},
  { 0.58095459f, 0.00000217f,-0.81393598f},
  { 0.f, 0.f, 1.f}, {-1.f, 0.f, 0.f}, { 0.f,-1.f, 0.f},
  { 0.f, 0.f,-1.f},
  {-0.10501402f,-0.17402183f, 0.97912636f},
  {-0.78718019f,-0.60474702f,-0.12094817f},
  {-0.58095459f, 0.00000217f,-0.81393598f},
  { 1.f, 0.f, 0.f}, { 0.f, 0.f, 1.f}, { 0.f, 1.f, 0.f},
  { 1.f, 0.f, 0.f}, { 0.f, 0.f, 1.f}, { 0.f, 1.f, 0.f},
  { 1.f, 0.f, 0.f}, { 0.f, 0.f, 1.f}, { 0.f, 1.f, 0.f},
  { 0.f, 1.f, 0.f}, { 0.f, 0.f,-1.f}, {-1.f, 0.f, 0.f},
  { 1.f, 0.f, 0.f}, { 0.f, 1.f, 0.f}, { 0.f, 0.f, 1.f},
  { 0.0494f, 0.0366f, 0.99810825f},
  {-0.01716099f, 0.99266564f,-0.11966796f},
  { 1.f, 0.f, 0.f}, { 0.f, 0.f,-1.f},
  { 0.f, 1.f, 0.f}, { 0.f, 0.f, 1.f}, { 1.f, 0.f, 0.f},
  { 1.f, 0.f, 0.f}, { 0.f, 1.f, 0.f}, { 0.f, 0.f, 1.f},
  {-0.0494f,-0.0366f, 0.99810825f},
  { 0.01716099f,-0.99266564f,-0.11966796f},
  {-1.f, 0.f, 0.f}, { 0.f, 0.f,-1.f},
  { 0.f, 0.f, 0.f}
};
__constant__ int c_ridx[24][3] = {
  {0,1,2},{3,4,5},{6,46,46},{7,46,46},{8,46,46},{9,46,46},
  {10,11,12},{13,46,46},{14,46,46},{15,46,46},{16,46,46},
  {17,18,19},{20,21,22},{23,24,25},{26,27,28},{29,30,31},
  {32,46,46},{33,46,46},{34,35,46},{36,37,38},{39,40,41},
  {42,46,46},{43,46,46},{44,45,46}
};
__constant__ int c_par[24] = {-1,0,1,2,3,4,0,6,7,8,9,0,11,12,12,14,15,16,17,12,19,20,21,22};

__device__ __forceinline__ void mm3(const float* A, const float* Bm, float* C) {
#pragma unroll
  for (int i = 0; i < 3; ++i)
#pragma unroll
    for (int j = 0; j < 3; ++j)
      C[i*3+j] = A[i*3+0]*Bm[0+j] + A[i*3+1]*Bm[3+j] + A[i*3+2]*Bm[6+j];
}
__device__ __forceinline__ void mm3_bt(const float* A, const float* Bm, float* C) {
#pragma unroll
  for (int i = 0; i < 3; ++i)
#pragma unroll
    for (int j = 0; j < 3; ++j)
      C[i*3+j] = A[i*3+0]*Bm[j*3+0] + A[i*3+1]*Bm[j*3+1] + A[i*3+2]*Bm[j*3+2];
}

// ---- K0: PD -> bf16 MFMA-B fragment layout pdm[c][vt][kt][lane][8] ----
// B-frag (16x16x32): col(v) = lane&15, k = (lane>>4)*8 + j
__global__ __launch_bounds__(256) void k0_pdm(const float* __restrict__ posed,
                                              const float* __restrict__ sd,
                                              const float* __restrict__ vt,
                                              unsigned short* __restrict__ pdm) {
  int t = blockIdx.x * 256 + threadIdx.x;      // exact grid: 3*432*7*64
  int lane = t & 63;
  int tile = t >> 6;
  int kt = tile % NKT;
  int vtg = (tile / NKT) % NVT;
  int c  = tile / (NKT * NVT);
  int v  = vtg*16 + (lane & 15);
  int kb = kt*32 + (lane >> 4)*8;
  unsigned short vals[8];
#pragma unroll
  for (int j = 0; j < 8; ++j) {
    int k = kb + j;
    float f = 0.f;
    if (v < V_) {
      if (k < 207)       f = posed[(v*3 + c)*207 + k];
      else if (k < 217)  f = sd[(v*3 + c)*10 + (k - 207)];
      else if (k == 217) f = vt[v*3 + c];
    }
    vals[j] = f2bf(f);
  }
  *(uint4*)(pdm + (size_t)tile*512 + lane*8) = *(const uint4*)vals;
}

// ---- K0c: skin weights -> bf16 A?-no: B-operand frags for GEMM2: smf[vt][slot][lane][8]
// cols(v) = lane&15, k(j) = (lane>>4)*8 + jj. slot0 = hi, slot1 = lo. Also zero jts.
__global__ __launch_bounds__(256) void k0c_smf(const float* __restrict__ sw,
                                               unsigned short* __restrict__ smf,
                                               float* __restrict__ jts) {
  if (blockIdx.x == 0) {
    for (int i = threadIdx.x; i < 24*33; i += 256) jts[i] = 0.f;
  }
  int t = blockIdx.x * 256 + threadIdx.x;      // exact: 432*2*64
  int lane = t & 63;
  int tile = t >> 6;
  int slot = tile & 1;
  int vtg  = tile >> 1;
  int v = vtg*16 + (lane & 15);
  int j0 = (lane >> 4) * 8;
  unsigned short vals[8];
#pragma unroll
  for (int jj = 0; jj < 8; ++jj) {
    int j = j0 + jj;
    float s = (v < V_ && j < NJ) ? sw[v*NJ + j] : 0.f;
    unsigned short hi = f2bf(s);
    vals[jj] = slot ? f2bf(s - bf2f(hi)) : hi;
  }
  *(uint4*)(smf + (size_t)tile*512 + lane*8) = *(const uint4*)vals;
}

// ---- K1: jts[j][c][0]=Jreg@vt ; jts[j][c][1+kb]=Jreg@sd. 8-way V-split + atomicAdd ----
__global__ __launch_bounds__(256) void k1_jts(const float* __restrict__ jreg,
                                              const float* __restrict__ vt,
                                              const float* __restrict__ sd,
                                              float* __restrict__ jts) {
  const int j = blockIdx.x % 24;
  const int chunk = blockIdx.x / 24;           // 0..7
  const int v0 = chunk * 864;
  const int v1 = (v0 + 864 < V_) ? v0 + 864 : V_;
  float acc[3][11];
#pragma unroll
  for (int c = 0; c < 3; ++c)
#pragma unroll
    for (int i = 0; i < 11; ++i) acc[c][i] = 0.f;
  for (int v = v0 + threadIdx.x; v < v1; v += 256) {
    float wgt = jreg[j*V_ + v];
#pragma unroll
    for (int c = 0; c < 3; ++c) {
      acc[c][0] += wgt * vt[v*3 + c];
      const float* s = sd + (v*3 + c)*10;
#pragma unroll
      for (int k = 0; k < 10; ++k) acc[c][1+k] += wgt * s[k];
    }
  }
#pragma unroll
  for (int c = 0; c < 3; ++c)
#pragma unroll
    for (int i = 0; i < 11; ++i)
#pragma unroll
      for (int o = 32; o > 0; o >>= 1) acc[c][i] += __shfl_xor(acc[c][i], o, 64);
  __shared__ float red[4][33];
  int wid = threadIdx.x >> 6, ln = threadIdx.x & 63;
  if (ln == 0) {
#pragma unroll
    for (int c = 0; c < 3; ++c)
#pragma unroll
      for (int i = 0; i < 11; ++i) red[wid][c*11+i] = acc[c][i];
  }
  __syncthreads();
  if (threadIdx.x < 33) {
    float s = red[0][threadIdx.x] + red[1][threadIdx.x] +
              red[2][threadIdx.x] + red[3][threadIdx.x];
    atomicAdd(&jts[j*33 + threadIdx.x], s);
  }
}

// ---- K2: per-batch pose math -> Fw[b][224] f32, Mw[b][24][12] f32 ----
__global__ void k2_pose(const float* __restrict__ poses, const float* __restrict__ betas,
                        const float* __restrict__ trans, const float* __restrict__ apose,
                        const float* __restrict__ pjr, const float* __restrict__ jts,
                        float* __restrict__ Fw, float* __restrict__ Mw) {
  const int b = blockIdx.x;
  const int t = threadIdx.x;
  __shared__ float Rd[47][9];
  __shared__ float Rj[24][9];
  __shared__ float Rl[24][9];
  __shared__ float jl[24][3];
  __shared__ float G[24][12];

  if (t < 47) {
    float q  = (t < NP) ? poses[b*NP + t] : 0.f;
    float ax = c_axes[t][0], ay = c_axes[t][1], az = c_axes[t][2];
    float s = sinf(q), cq = cosf(q);
    float u = 1.f - cq;
    Rd[t][0] = u*ax*ax + cq;   Rd[t][1] = u*ax*ay - s*az; Rd[t][2] = u*ax*az + s*ay;
    Rd[t][3] = u*ax*ay + s*az; Rd[t][4] = u*ay*ay + cq;   Rd[t][5] = u*ay*az - s*ax;
    Rd[t][6] = u*ax*az - s*ay; Rd[t][7] = u*ay*az + s*ax; Rd[t][8] = u*az*az + cq;
  }
  if (t < NJ) {
    const float* jr = jts + t*33;
#pragma unroll
    for (int c = 0; c < 3; ++c) {
      float a = jr[c*11];
#pragma unroll
      for (int k = 0; k < 10; ++k) a += jr[c*11 + 1 + k] * betas[b*10 + k];
      jl[t][c] = a;
    }
  }
  __syncthreads();
  if (t < NJ) {
    float C1[9], C2[9];
    const int r0 = c_ridx[t][0], r1 = c_ridx[t][1], r2 = c_ridx[t][2];
    mm3(&Rd[r0][0], &Rd[r1][0], C1);
    mm3(C1, &Rd[r2][0], C2);
#pragma unroll
    for (int e = 0; e < 9; ++e) Rj[t][e] = C2[e];
    float P[9], Ap[9];
#pragma unroll
    for (int e = 0; e < 9; ++e) { P[e] = pjr[t*9 + e]; Ap[e] = apose[t*9 + e]; }
    mm3(P, C2, C1);
    mm3_bt(C1, P, C2);
    mm3(Ap, C2, C1);
#pragma unroll
    for (int e = 0; e < 9; ++e) Rl[t][e] = C1[e];
  }
  __syncthreads();
  if (t == 0) {
#pragma unroll
    for (int e = 0; e < 9; ++e) G[0][e] = Rl[0][e];
    G[0][9] = jl[0][0]; G[0][10] = jl[0][1]; G[0][11] = jl[0][2];
    for (int j = 1; j < NJ; ++j) {
      int p = c_par[j];
      float R[9];
      mm3(&G[p][0], &Rl[j][0], R);
#pragma unroll
      for (int e = 0; e < 9; ++e) G[j][e] = R[e];
      float d0 = jl[j][0]-jl[p][0], d1 = jl[j][1]-jl[p][1], d2 = jl[j][2]-jl[p][2];
      G[j][9]  = G[p][9]  + G[p][0]*d0 + G[p][1]*d1 + G[p][2]*d2;
      G[j][10] = G[p][10] + G[p][3]*d0 + G[p][4]*d1 + G[p][5]*d2;
      G[j][11] = G[p][11] + G[p][6]*d0 + G[p][7]*d1 + G[p][8]*d2;
    }
  }
  __syncthreads();
  if (t < NJ) {
    float tx = trans[b*3+0], ty = trans[b*3+1], tz = trans[b*3+2];
    float a0 = G[t][9]  - (G[t][0]*jl[t][0] + G[t][1]*jl[t][1] + G[t][2]*jl[t][2]) + tx;
    float a1 = G[t][10] - (G[t][3]*jl[t][0] + G[t][4]*jl[t][1] + G[t][5]*jl[t][2]) + ty;
    float a2 = G[t][11] - (G[t][6]*jl[t][0] + G[t][7]*jl[t][1] + G[t][8]*jl[t][2]) + tz;
    float* m = Mw + b*288 + t*12;
#pragma unroll
    for (int e = 0; e < 9; ++e) m[e] = G[t][e];
    m[9] = a0; m[10] = a1; m[11] = a2;
  }
  for (int k = t; k < KF; k += 64) {
    float val;
    if (k < 207) {
      int jj = k / 9 + 1;
      int e  = k % 9;
      val = Rj[jj][e] - ((e == 0 || e == 4 || e == 8) ? 1.f : 0.f);
    } else if (k < 217) val = betas[b*10 + (k - 207)];
    else if (k == 217)  val = 1.f;
    else                val = 0.f;
    Fw[b*KF + k] = val;
  }
}

// ---- K2b: F -> bf16 MFMA-A frags fmf[bt][kt][lane][8]: row(b)=lane&15 ----
__global__ void k2b_fmf(const float* __restrict__ Fw, unsigned short* __restrict__ fmf) {
  int t = blockIdx.x * 256 + threadIdx.x;      // exact: 32*7*64
  int lane = t & 63;
  int tile = t >> 6;
  int kt = tile % NKT;
  int bt = tile / NKT;
  int b  = bt*16 + (lane & 15);
  int kb = kt*32 + (lane >> 4)*8;
  unsigned short vals[8];
#pragma unroll
  for (int j = 0; j < 8; ++j) vals[j] = f2bf(Fw[b*KF + kb + j]);
  *(uint4*)(fmf + (size_t)tile*512 + lane*8) = *(const uint4*)vals;
}

// ---- K2c: Mw -> bf16 MFMA-A frags for GEMM2: mmf[e][bt][slot][lane][8] ----
// row(b) = lane&15, k(j) = (lane>>4)*8 + jj. slot: 0=hi, 1=lo, 2=hi
__global__ void k2c_mmf(const float* __restrict__ Mw, unsigned short* __restrict__ mmf) {
  int t = blockIdx.x * 256 + threadIdx.x;      // exact: 12*32*3*64
  int lane = t & 63;
  int tile = t >> 6;
  int slot = tile % 3;
  int bt   = (tile / 3) % NBT;
  int e    = tile / (3*NBT);
  int b  = bt*16 + (lane & 15);
  int j0 = (lane >> 4) * 8;
  unsigned short vals[8];
#pragma unroll
  for (int jj = 0; jj < 8; ++jj) {
    int j = j0 + jj;
    float f = (j < NJ) ? Mw[b*288 + j*12 + e] : 0.f;
    unsigned short hi = f2bf(f);
    vals[jj] = (slot == 1) ? f2bf(f - bf2f(hi)) : hi;
  }
  *(uint4*)(mmf + (size_t)tile*512 + lane*8) = *(const uint4*)vals;
}

// ---- K3: GEMM1 (p = F@PD) + GEMM2 (W = M@S) + combine, all MFMA ----
// block = 8 waves = 2 vtg x 4 btg; wave tile 16b x 16v.
// C layout: row(b) = (lane>>4)*4 + q, col(v) = lane&15
__global__ __launch_bounds__(512) void k3_verts(
    const unsigned short* __restrict__ pdm,  // [3][432][7][512]
    const unsigned short* __restrict__ fmf,  // [32][7][512]
    const unsigned short* __restrict__ smf,  // [432][2][512]
    const unsigned short* __restrict__ mmf,  // [12][32][3][512]
    float* __restrict__ out)                 // [B][V][3]
{
  const int t    = threadIdx.x;
  const int lane = t & 63;
  const int w    = t >> 6;                   // 0..7
  const int wv   = w >> 2, wb = w & 3;
  const int bt_blk = blockIdx.x & 7;         // fastest: 8 blocks share PD slice
  const int vt_blk = blockIdx.x >> 3;        // 0..215
  const int vtg = vt_blk*2 + wv;
  const int btg = bt_blk*4 + wb;

  f32x4 acc1[3];
#pragma unroll
  for (int c = 0; c < 3; ++c) acc1[c] = (f32x4){0.f,0.f,0.f,0.f};

  // GEMM1: p[b][v][c]
#pragma unroll 2
  for (int kt = 0; kt < NKT; ++kt) {
    s16x8 fa = *(const s16x8*)(fmf + ((size_t)btg*NKT + kt)*512 + lane*8);
#pragma unroll
    for (int c = 0; c < 3; ++c) {
      s16x8 pb = *(const s16x8*)(pdm + (((size_t)c*NVT + vtg)*NKT + kt)*512 + lane*8);
      acc1[c] = __builtin_amdgcn_mfma_f32_16x16x32_bf16(fa, pb, acc1[c], 0, 0, 0);
    }
  }

  // GEMM2: W[b][v][e] = sum_j M[b][j][e] * s[v][j], 3-term hi/lo split
  f32x4 wacc[12];
#pragma unroll
  for (int e = 0; e < 12; ++e) wacc[e] = (f32x4){0.f,0.f,0.f,0.f};

  s16x8 sh = *(const s16x8*)(smf + ((size_t)vtg*2 + 0)*512 + lane*8);
  s16x8 sl = *(const s16x8*)(smf + ((size_t)vtg*2 + 1)*512 + lane*8);

#pragma unroll
  for (int e = 0; e < 12; ++e) {
    s16x8 m0 = *(const s16x8*)(mmf + (((size_t)e*NBT + btg)*3 + 0)*512 + lane*8);
    wacc[e] = __builtin_amdgcn_mfma_f32_16x16x32_bf16(m0, sh, wacc[e], 0, 0, 0);
  }
#pragma unroll
  for (int e = 0; e < 12; ++e) {
    s16x8 m1 = *(const s16x8*)(mmf + (((size_t)e*NBT + btg)*3 + 1)*512 + lane*8);
    wacc[e] = __builtin_amdgcn_mfma_f32_16x16x32_bf16(m1, sh, wacc[e], 0, 0, 0);
  }
#pragma unroll
  for (int e = 0; e < 12; ++e) {
    s16x8 m2 = *(const s16x8*)(mmf + (((size_t)e*NBT + btg)*3 + 2)*512 + lane*8);
    wacc[e] = __builtin_amdgcn_mfma_f32_16x16x32_bf16(m2, sl, wacc[e], 0, 0, 0);
  }

  // combine + store: vert[m] = W[3m]x + W[3m+1]y + W[3m+2]z + W[9+m]
  const int v = vtg*16 + (lane & 15);
  if (v < V_) {
    const int b0 = btg*16 + (lane >> 4)*4;
#pragma unroll
    for (int q = 0; q < 4; ++q) {
      float x = acc1[0][q], y = acc1[1][q], z = acc1[2][q];
      float o0 = fmaf(wacc[2][q], z, fmaf(wacc[1][q], y, fmaf(wacc[0][q], x, wacc[ 9][q])));
      float o1 = fmaf(wacc[5][q], z, fmaf(wacc[4][q], y, fmaf(wacc[3][q], x, wacc[10][q])));
      float o2 = fmaf(wacc[8][q], z, fmaf(wacc[7][q], y, fmaf(wacc[6][q], x, wacc[11][q])));
      float* op = out + ((size_t)(b0 + q)*V_ + v)*3;
      op[0] = o0; op[1] = o1; op[2] = o2;
    }
  }
}

extern "C" void kernel_launch(void* const* d_in, const int* in_sizes, int n_in,
                              void* d_out, int out_size, void* d_ws, size_t ws_size,
                              hipStream_t stream) {
  (void)in_sizes; (void)n_in; (void)out_size; (void)ws_size;
  const float* betas      = (const float*)d_in[0];
  const float* poses      = (const float*)d_in[1];
  const float* trans      = (const float*)d_in[2];
  const float* v_template = (const float*)d_in[3];
  const float* shapedirs  = (const float*)d_in[4];
  const float* posedirs   = (const float*)d_in[5];
  const float* jreg       = (const float*)d_in[6];
  const float* skinw      = (const float*)d_in[7];
  const float* apose      = (const float*)d_in[8];
  const float* pjr        = (const float*)d_in[9];
  float* out = (float*)d_out;
  float* ws  = (float*)d_ws;

  unsigned short* pdm = (unsigned short*)ws;              // 3*432*7*512 u16 = 2,322,432 f32
  unsigned short* fmf = (unsigned short*)(ws + 2322432);  // 32*7*512  u16 =    57,344 f32
  unsigned short* smf = (unsigned short*)(ws + 2379776);  // 432*2*512 u16 =   221,184 f32
  unsigned short* mmf = (unsigned short*)(ws + 2600960);  // 12*32*3*512 u16 = 294,912 f32
  float* Fw  = ws + 2895872;                              // 512*224 = 114,688
  float* Mw  = ws + 3010560;                              // 512*288 = 147,456
  float* jts = ws + 3158016;                              // 24*33   = 792  (end ~12.6 MB)

  hipLaunchKernelGGL(k0_pdm, dim3(3*NVT*NKT*64/256), dim3(256), 0, stream,
                     posedirs, shapedirs, v_template, pdm);
  hipLaunchKernelGGL(k0c_smf, dim3(NVT*2*64/256), dim3(256), 0, stream, skinw, smf, jts);
  hipLaunchKernelGGL(k1_jts, dim3(24*8), dim3(256), 0, stream,
                     jreg, v_template, shapedirs, jts);
  hipLaunchKernelGGL(k2_pose, dim3(B_), dim3(64), 0, stream,
                     poses, betas, trans, apose, pjr, jts, Fw, Mw);
  hipLaunchKernelGGL(k2b_fmf, dim3(NBT*NKT*64/256), dim3(256), 0, stream, Fw, fmf);
  hipLaunchKernelGGL(k2c_mmf, dim3(12*NBT*3*64/256), dim3(256), 0, stream, Mw, mmf);
  hipLaunchKernelGGL(k3_verts, dim3(8 * 216), dim3(512), 0, stream,
                     pdm, fmf, smf, mmf, out);
}

// Round 5
// 70.926 us; speedup vs baseline: 9.3108x; 1.1278x over previous
//
#include <hip/hip_runtime.h>
#include <cstdint>
#include <cstddef>

#define B_   512
#define V_   6890
#define VP   6912      // padded vertex count (432*16)
#define NJ   24
#define KF   224       // padded K: 207 pose + 10 betas + 1 + 6 pad (7 tiles of 32)
#define NP   46
#define NVT  432       // 16-v tiles
#define NBT  32        // 16-b tiles
#define NKT  7         // 32-k tiles

typedef float f32x4 __attribute__((ext_vector_type(4)));
typedef short s16x8 __attribute__((ext_vector_type(8)));

__device__ __forceinline__ unsigned short f2bf(float f) {
  unsigned int u = __float_as_uint(f);
  u = (u + 0x7FFFu + ((u >> 16) & 1u)) >> 16;
  return (unsigned short)u;
}
__device__ __forceinline__ float bf2f(unsigned short h) {
  return __uint_as_float(((unsigned int)h) << 16);
}

// ---- constants ----
__constant__ float c_axes[47][3] = {
  { 0.f, 0.f, 1.f}, { 1.f, 0.f, 0.f}, { 0.f, 1.f, 0.f},
  { 0.f, 0.f, 1.f}, { 1.f, 0.f, 0.f}, { 0.f, 1.f, 0.f},
  { 0.f, 0.f,-1.f},
  {-0.10501402f,-0.17402183f, 0.97912636f},
  { 0.78718019f, 0.60474702f,-0.12094817f},
  { 0.58095459f, 0.00000217f,-0.81393598f},
  { 0.f, 0.f, 1.f}, {-1.f, 0.f, 0.f}, { 0.f,-1.f, 0.f},
  { 0.f, 0.f,-1.f},
  {-0.10501402f,-0.17402183f, 0.97912636f},
  {-0.78718019f,-0.60474702f,-0.12094817f},
  {-0.58095459f, 0.00000217f,-0.81393598f},
  { 1.f, 0.f, 0.f}, { 0.f, 0.f, 1.f}, { 0.f, 1.f, 0.f},
  { 1.f, 0.f, 0.f}, { 0.f, 0.f, 1.f}, { 0.f, 1.f, 0.f},
  { 1.f, 0.f, 0.f}, { 0.f, 0.f, 1.f}, { 0.f, 1.f, 0.f},
  { 0.f, 1.f, 0.f}, { 0.f, 0.f,-1.f}, {-1.f, 0.f, 0.f},
  { 1.f, 0.f, 0.f}, { 0.f, 1.f, 0.f}, { 0.f, 0.f, 1.f},
  { 0.0494f, 0.0366f, 0.99810825f},
  {-0.01716099f, 0.99266564f,-0.11966796f},
  { 1.f, 0.f, 0.f}, { 0.f, 0.f,-1.f},
  { 0.f, 1.f, 0.f}, { 0.f, 0.f, 1.f}, { 1.f, 0.f, 0.f},
  { 1.f, 0.f, 0.f}, { 0.f, 1.f, 0.f}, { 0.f, 0.f, 1.f},
  {-0.0494f,-0.0366f, 0.99810825f},
  { 0.01716099f,-0.99266564f,-0.11966796f},
  {-1.f, 0.f, 0.f}, { 0.f, 0.f,-1.f},
  { 0.f, 0.f, 0.f}
};
__constant__ int c_ridx[24][3] = {
  {0,1,2},{3,4,5},{6,46,46},{7,46,46},{8,46,46},{9,46,46},
  {10,11,12},{13,46,46},{14,46,46},{15,46,46},{16,46,46},
  {17,18,19},{20,21,22},{23,24,25},{26,27,28},{29,30,31},
  {32,46,46},{33,46,46},{34,35,46},{36,37,38},{39,40,41},
  {42,46,46},{43,46,46},{44,45,46}
};
__constant__ int c_par[24] = {-1,0,1,2,3,4,0,6,7,8,9,0,11,12,12,14,15,16,17,12,19,20,21,22};

__device__ __forceinline__ void mm3(const float* A, const float* Bm, float* C) {
#pragma unroll
  for (int i = 0; i < 3; ++i)
#pragma unroll
    for (int j = 0; j < 3; ++j)
      C[i*3+j] = A[i*3+0]*Bm[0+j] + A[i*3+1]*Bm[3+j] + A[i*3+2]*Bm[6+j];
}
__device__ __forceinline__ void mm3_bt(const float* A, const float* Bm, float* C) {
#pragma unroll
  for (int i = 0; i < 3; ++i)
#pragma unroll
    for (int j = 0; j < 3; ++j)
      C[i*3+j] = A[i*3+0]*Bm[j*3+0] + A[i*3+1]*Bm[j*3+1] + A[i*3+2]*Bm[j*3+2];
}

// ---- K0: fused static prep ----
// blocks [0,2268): pdm[c][vt][kt][lane][8]  B-frag: col(v)=lane&15, k=(lane>>4)*8+j
// blocks [2268,2484): smf[vt][slot][lane][8] B-frag: col(v)=lane&15, k(j)=(lane>>4)*8+jj
//                     slot0=hi(s), slot1=lo(s).  block 2268 also zeroes jts.
__global__ __launch_bounds__(256) void k0_prep(const float* __restrict__ posed,
                                               const float* __restrict__ sd,
                                               const float* __restrict__ vt,
                                               const float* __restrict__ sw,
                                               unsigned short* __restrict__ pdm,
                                               unsigned short* __restrict__ smf,
                                               float* __restrict__ jts) {
  const int lane = threadIdx.x & 63;
  if (blockIdx.x < 2268) {
    int tile = blockIdx.x * 4 + (threadIdx.x >> 6);   // 0..9071
    int kt = tile % NKT;
    int vtg = (tile / NKT) % NVT;
    int c  = tile / (NKT * NVT);
    int v  = vtg*16 + (lane & 15);
    int kb = kt*32 + (lane >> 4)*8;
    unsigned short vals[8];
#pragma unroll
    for (int j = 0; j < 8; ++j) {
      int k = kb + j;
      float f = 0.f;
      if (v < V_) {
        if (k < 207)       f = posed[(v*3 + c)*207 + k];
        else if (k < 217)  f = sd[(v*3 + c)*10 + (k - 207)];
        else if (k == 217) f = vt[v*3 + c];
      }
      vals[j] = f2bf(f);
    }
    *(uint4*)(pdm + (size_t)tile*512 + lane*8) = *(const uint4*)vals;
  } else {
    if (blockIdx.x == 2268) {
      for (int i = threadIdx.x; i < 24*33; i += 256) jts[i] = 0.f;
    }
    int tile = (blockIdx.x - 2268) * 4 + (threadIdx.x >> 6);  // 0..863
    int slot = tile & 1;
    int vtg  = tile >> 1;
    int v = vtg*16 + (lane & 15);
    int j0 = (lane >> 4) * 8;
    unsigned short vals[8];
#pragma unroll
    for (int jj = 0; jj < 8; ++jj) {
      int j = j0 + jj;
      float s = (v < V_ && j < NJ) ? sw[v*NJ + j] : 0.f;
      unsigned short hi = f2bf(s);
      vals[jj] = slot ? f2bf(s - bf2f(hi)) : hi;
    }
    *(uint4*)(smf + (size_t)tile*512 + lane*8) = *(const uint4*)vals;
  }
}

// ---- K1: jts[j][c][0]=Jreg@vt ; jts[j][c][1+kb]=Jreg@sd. 8-way V-split + atomicAdd ----
__global__ __launch_bounds__(256) void k1_jts(const float* __restrict__ jreg,
                                              const float* __restrict__ vt,
                                              const float* __restrict__ sd,
                                              float* __restrict__ jts) {
  const int j = blockIdx.x % 24;
  const int chunk = blockIdx.x / 24;           // 0..7
  const int v0 = chunk * 864;
  const int v1 = (v0 + 864 < V_) ? v0 + 864 : V_;
  float acc[3][11];
#pragma unroll
  for (int c = 0; c < 3; ++c)
#pragma unroll
    for (int i = 0; i < 11; ++i) acc[c][i] = 0.f;
  for (int v = v0 + threadIdx.x; v < v1; v += 256) {
    float wgt = jreg[j*V_ + v];
#pragma unroll
    for (int c = 0; c < 3; ++c) {
      acc[c][0] += wgt * vt[v*3 + c];
      const float* s = sd + (v*3 + c)*10;
#pragma unroll
      for (int k = 0; k < 10; ++k) acc[c][1+k] += wgt * s[k];
    }
  }
#pragma unroll
  for (int c = 0; c < 3; ++c)
#pragma unroll
    for (int i = 0; i < 11; ++i)
#pragma unroll
      for (int o = 32; o > 0; o >>= 1) acc[c][i] += __shfl_xor(acc[c][i], o, 64);
  __shared__ float red[4][33];
  int wid = threadIdx.x >> 6, ln = threadIdx.x & 63;
  if (ln == 0) {
#pragma unroll
    for (int c = 0; c < 3; ++c)
#pragma unroll
      for (int i = 0; i < 11; ++i) red[wid][c*11+i] = acc[c][i];
  }
  __syncthreads();
  if (threadIdx.x < 33) {
    float s = red[0][threadIdx.x] + red[1][threadIdx.x] +
              red[2][threadIdx.x] + red[3][threadIdx.x];
    atomicAdd(&jts[j*33 + threadIdx.x], s);
  }
}

// ---- K2: per-batch pose math -> Fw[b][224] f32, Mw[b][24][12] f32 ----
__global__ void k2_pose(const float* __restrict__ poses, const float* __restrict__ betas,
                        const float* __restrict__ trans, const float* __restrict__ apose,
                        const float* __restrict__ pjr, const float* __restrict__ jts,
                        float* __restrict__ Fw, float* __restrict__ Mw) {
  const int b = blockIdx.x;
  const int t = threadIdx.x;
  __shared__ float Rd[47][9];
  __shared__ float Rj[24][9];
  __shared__ float Rl[24][9];
  __shared__ float jl[24][3];
  __shared__ float G[24][12];

  if (t < 47) {
    float q  = (t < NP) ? poses[b*NP + t] : 0.f;
    float ax = c_axes[t][0], ay = c_axes[t][1], az = c_axes[t][2];
    float s = sinf(q), cq = cosf(q);
    float u = 1.f - cq;
    Rd[t][0] = u*ax*ax + cq;   Rd[t][1] = u*ax*ay - s*az; Rd[t][2] = u*ax*az + s*ay;
    Rd[t][3] = u*ax*ay + s*az; Rd[t][4] = u*ay*ay + cq;   Rd[t][5] = u*ay*az - s*ax;
    Rd[t][6] = u*ax*az - s*ay; Rd[t][7] = u*ay*az + s*ax; Rd[t][8] = u*az*az + cq;
  }
  if (t < NJ) {
    const float* jr = jts + t*33;
#pragma unroll
    for (int c = 0; c < 3; ++c) {
      float a = jr[c*11];
#pragma unroll
      for (int k = 0; k < 10; ++k) a += jr[c*11 + 1 + k] * betas[b*10 + k];
      jl[t][c] = a;
    }
  }
  __syncthreads();
  if (t < NJ) {
    float C1[9], C2[9];
    const int r0 = c_ridx[t][0], r1 = c_ridx[t][1], r2 = c_ridx[t][2];
    mm3(&Rd[r0][0], &Rd[r1][0], C1);
    mm3(C1, &Rd[r2][0], C2);
#pragma unroll
    for (int e = 0; e < 9; ++e) Rj[t][e] = C2[e];
    float P[9], Ap[9];
#pragma unroll
    for (int e = 0; e < 9; ++e) { P[e] = pjr[t*9 + e]; Ap[e] = apose[t*9 + e]; }
    mm3(P, C2, C1);
    mm3_bt(C1, P, C2);
    mm3(Ap, C2, C1);
#pragma unroll
    for (int e = 0; e < 9; ++e) Rl[t][e] = C1[e];
  }
  __syncthreads();
  if (t == 0) {
#pragma unroll
    for (int e = 0; e < 9; ++e) G[0][e] = Rl[0][e];
    G[0][9] = jl[0][0]; G[0][10] = jl[0][1]; G[0][11] = jl[0][2];
    for (int j = 1; j < NJ; ++j) {
      int p = c_par[j];
      float R[9];
      mm3(&G[p][0], &Rl[j][0], R);
#pragma unroll
      for (int e = 0; e < 9; ++e) G[j][e] = R[e];
      float d0 = jl[j][0]-jl[p][0], d1 = jl[j][1]-jl[p][1], d2 = jl[j][2]-jl[p][2];
      G[j][9]  = G[p][9]  + G[p][0]*d0 + G[p][1]*d1 + G[p][2]*d2;
      G[j][10] = G[p][10] + G[p][3]*d0 + G[p][4]*d1 + G[p][5]*d2;
      G[j][11] = G[p][11] + G[p][6]*d0 + G[p][7]*d1 + G[p][8]*d2;
    }
  }
  __syncthreads();
  if (t < NJ) {
    float tx = trans[b*3+0], ty = trans[b*3+1], tz = trans[b*3+2];
    float a0 = G[t][9]  - (G[t][0]*jl[t][0] + G[t][1]*jl[t][1] + G[t][2]*jl[t][2]) + tx;
    float a1 = G[t][10] - (G[t][3]*jl[t][0] + G[t][4]*jl[t][1] + G[t][5]*jl[t][2]) + ty;
    float a2 = G[t][11] - (G[t][6]*jl[t][0] + G[t][7]*jl[t][1] + G[t][8]*jl[t][2]) + tz;
    float* m = Mw + b*288 + t*12;
#pragma unroll
    for (int e = 0; e < 9; ++e) m[e] = G[t][e];
    m[9] = a0; m[10] = a1; m[11] = a2;
  }
  for (int k = t; k < KF; k += 64) {
    float val;
    if (k < 207) {
      int jj = k / 9 + 1;
      int e  = k % 9;
      val = Rj[jj][e] - ((e == 0 || e == 4 || e == 8) ? 1.f : 0.f);
    } else if (k < 217) val = betas[b*10 + (k - 207)];
    else if (k == 217)  val = 1.f;
    else                val = 0.f;
    Fw[b*KF + k] = val;
  }
}

// ---- K2bc: fused fragment prep for F and M ----
// blocks [0,56): fmf[bt][kt][lane][8]  A-frag: row(b)=lane&15, k=(lane>>4)*8+j
// blocks [56,248): mmf[e][bt][slot][lane][8]  A-frag rows=b, k(j); slot0=hi, slot1=lo
__global__ __launch_bounds__(256) void k2bc_frag(const float* __restrict__ Fw,
                                                 const float* __restrict__ Mw,
                                                 unsigned short* __restrict__ fmf,
                                                 unsigned short* __restrict__ mmf) {
  const int lane = threadIdx.x & 63;
  if (blockIdx.x < 56) {
    int tile = blockIdx.x * 4 + (threadIdx.x >> 6);   // 0..223
    int kt = tile % NKT;
    int bt = tile / NKT;
    int b  = bt*16 + (lane & 15);
    int kb = kt*32 + (lane >> 4)*8;
    unsigned short vals[8];
#pragma unroll
    for (int j = 0; j < 8; ++j) vals[j] = f2bf(Fw[b*KF + kb + j]);
    *(uint4*)(fmf + (size_t)tile*512 + lane*8) = *(const uint4*)vals;
  } else {
    int tile = (blockIdx.x - 56) * 4 + (threadIdx.x >> 6);  // 0..767
    int slot = tile & 1;
    int bt   = (tile >> 1) % NBT;
    int e    = tile / (2*NBT);
    int b  = bt*16 + (lane & 15);
    int j0 = (lane >> 4) * 8;
    unsigned short vals[8];
#pragma unroll
    for (int jj = 0; jj < 8; ++jj) {
      int j = j0 + jj;
      float f = (j < NJ) ? Mw[b*288 + j*12 + e] : 0.f;
      unsigned short hi = f2bf(f);
      vals[jj] = slot ? f2bf(f - bf2f(hi)) : hi;
    }
    *(uint4*)(mmf + (size_t)tile*512 + lane*8) = *(const uint4*)vals;
  }
}

// ---- K3: GEMM1 (p = F@PD) + GEMM2 (W = M@S, e-loop) + combine, all MFMA ----
// block = 8 waves = 4 wv x 2 wb; wave tile = 2 vtg x 2 btg (32v x 32b).
// C layout: row(b) = (lane>>4)*4 + q, col(v) = lane&15
__global__ __launch_bounds__(512) void k3_verts(
    const unsigned short* __restrict__ pdm,  // [3][432][7][512]
    const unsigned short* __restrict__ fmf,  // [32][7][512]
    const unsigned short* __restrict__ smf,  // [432][2][512]
    const unsigned short* __restrict__ mmf,  // [12][32][2][512]
    float* __restrict__ out)                 // [B][V][3]
{
  // bijective XCD swizzle: grid 432 = 8*54; keep bt-sibling groups on one XCD
  const int wg   = (blockIdx.x & 7) * 54 + (blockIdx.x >> 3);
  const int bt_blk = wg & 7;                 // 0..7  (4 btg each)
  const int vt_blk = wg >> 3;                // 0..53 (8 vtg each)
  const int t    = threadIdx.x;
  const int lane = t & 63;
  const int w    = t >> 6;                   // 0..7
  const int wv   = w >> 1, wb = w & 1;
  const int vtg0 = vt_blk*8 + wv*2;
  const int btg0 = bt_blk*4 + wb*2;

  f32x4 acc1[2][2][3];
#pragma unroll
  for (int vs = 0; vs < 2; ++vs)
#pragma unroll
    for (int bs = 0; bs < 2; ++bs)
#pragma unroll
      for (int c = 0; c < 3; ++c) acc1[vs][bs][c] = (f32x4){0.f,0.f,0.f,0.f};

  // GEMM1: p[b][v][c] = sum_k F[b][k] PD[k][v][c]
#pragma unroll 1
  for (int kt = 0; kt < NKT; ++kt) {
    s16x8 fa[2], pb[2][3];
#pragma unroll
    for (int bs = 0; bs < 2; ++bs)
      fa[bs] = *(const s16x8*)(fmf + ((size_t)(btg0+bs)*NKT + kt)*512 + lane*8);
#pragma unroll
    for (int vs = 0; vs < 2; ++vs)
#pragma unroll
      for (int c = 0; c < 3; ++c)
        pb[vs][c] = *(const s16x8*)(pdm + (((size_t)c*NVT + vtg0+vs)*NKT + kt)*512 + lane*8);
#pragma unroll
    for (int vs = 0; vs < 2; ++vs)
#pragma unroll
      for (int bs = 0; bs < 2; ++bs)
#pragma unroll
        for (int c = 0; c < 3; ++c)
          acc1[vs][bs][c] = __builtin_amdgcn_mfma_f32_16x16x32_bf16(fa[bs], pb[vs][c], acc1[vs][bs][c], 0, 0, 0);
  }

  // GEMM2 + combine: W_e = sum_j M[b][j][e] s[v][j]  (3-term hi/lo, 2 stored slots)
  s16x8 sh[2], sl[2];
#pragma unroll
  for (int vs = 0; vs < 2; ++vs) {
    sh[vs] = *(const s16x8*)(smf + ((size_t)(vtg0+vs)*2 + 0)*512 + lane*8);
    sl[vs] = *(const s16x8*)(smf + ((size_t)(vtg0+vs)*2 + 1)*512 + lane*8);
  }

  f32x4 vo[2][2][3];
#pragma unroll
  for (int vs = 0; vs < 2; ++vs)
#pragma unroll
    for (int bs = 0; bs < 2; ++bs)
#pragma unroll
      for (int m = 0; m < 3; ++m) vo[vs][bs][m] = (f32x4){0.f,0.f,0.f,0.f};

#pragma unroll
  for (int e = 0; e < 12; ++e) {
    s16x8 mh[2], ml[2];
#pragma unroll
    for (int bs = 0; bs < 2; ++bs) {
      mh[bs] = *(const s16x8*)(mmf + (((size_t)e*NBT + btg0+bs)*2 + 0)*512 + lane*8);
      ml[bs] = *(const s16x8*)(mmf + (((size_t)e*NBT + btg0+bs)*2 + 1)*512 + lane*8);
    }
#pragma unroll
    for (int vs = 0; vs < 2; ++vs)
#pragma unroll
      for (int bs = 0; bs < 2; ++bs) {
        f32x4 tmp = (f32x4){0.f,0.f,0.f,0.f};
        tmp = __builtin_amdgcn_mfma_f32_16x16x32_bf16(mh[bs], sh[vs], tmp, 0, 0, 0);
        tmp = __builtin_amdgcn_mfma_f32_16x16x32_bf16(ml[bs], sh[vs], tmp, 0, 0, 0);
        tmp = __builtin_amdgcn_mfma_f32_16x16x32_bf16(mh[bs], sl[vs], tmp, 0, 0, 0);
        if (e < 9) vo[vs][bs][e/3] += tmp * acc1[vs][bs][e%3];
        else       vo[vs][bs][e-9] += tmp;
      }
  }

#pragma unroll
  for (int vs = 0; vs < 2; ++vs) {
    const int v = (vtg0+vs)*16 + (lane & 15);
    if (v < V_) {
#pragma unroll
      for (int bs = 0; bs < 2; ++bs) {
        const int b0 = (btg0+bs)*16 + (lane >> 4)*4;
#pragma unroll
        for (int q = 0; q < 4; ++q) {
          float* op = out + ((size_t)(b0 + q)*V_ + v)*3;
          op[0] = vo[vs][bs][0][q];
          op[1] = vo[vs][bs][1][q];
          op[2] = vo[vs][bs][2][q];
        }
      }
    }
  }
}

extern "C" void kernel_launch(void* const* d_in, const int* in_sizes, int n_in,
                              void* d_out, int out_size, void* d_ws, size_t ws_size,
                              hipStream_t stream) {
  (void)in_sizes; (void)n_in; (void)out_size; (void)ws_size;
  const float* betas      = (const float*)d_in[0];
  const float* poses      = (const float*)d_in[1];
  const float* trans      = (const float*)d_in[2];
  const float* v_template = (const float*)d_in[3];
  const float* shapedirs  = (const float*)d_in[4];
  const float* posedirs   = (const float*)d_in[5];
  const float* jreg       = (const float*)d_in[6];
  const float* skinw      = (const float*)d_in[7];
  const float* apose      = (const float*)d_in[8];
  const float* pjr        = (const float*)d_in[9];
  float* out = (float*)d_out;
  float* ws  = (float*)d_ws;

  unsigned short* pdm = (unsigned short*)ws;              // 3*432*7*512 u16 = 2,322,432 f32
  unsigned short* fmf = (unsigned short*)(ws + 2322432);  // 224*512  u16 =    57,344 f32
  unsigned short* smf = (unsigned short*)(ws + 2379776);  // 864*512  u16 =   221,184 f32
  unsigned short* mmf = (unsigned short*)(ws + 2600960);  // 768*512  u16 =   196,608 f32
  float* Fw  = ws + 2797568;                              // 512*224 = 114,688
  float* Mw  = ws + 2912256;                              // 512*288 = 147,456
  float* jts = ws + 3059712;                              // 24*33   = 792  (end ~12.2 MB)

  hipLaunchKernelGGL(k0_prep, dim3(2484), dim3(256), 0, stream,
                     posedirs, shapedirs, v_template, skinw, pdm, smf, jts);
  hipLaunchKernelGGL(k1_jts, dim3(24*8), dim3(256), 0, stream,
                     jreg, v_template, shapedirs, jts);
  hipLaunchKernelGGL(k2_pose, dim3(B_), dim3(64), 0, stream,
                     poses, betas, trans, apose, pjr, jts, Fw, Mw);
  hipLaunchKernelGGL(k2bc_frag, dim3(248), dim3(256), 0, stream, Fw, Mw, fmf, mmf);
  hipLaunchKernelGGL(k3_verts, dim3(432), dim3(512), 0, stream,
                     pdm, fmf, smf, mmf, out);
}